// Round 11
// baseline (187.600 us; speedup 1.0000x reference)
//
#include <hip/hip_runtime.h>

// Problem constants
#define N_TOTAL   65536   // B*H*W = 64*32*32
#define HW_SZ     1024    // H*W
#define CDIM      64      // embedding dim (= C)
#define K_CODES   1024
#define OUT_ELEMS 4194304 // 64*64*32*32
#define QT        128     // queries per argmin block
#define CHUNK     64      // codes per LDS chunk (double-buffered)
#define NCHUNK    (K_CODES / CHUNK)   // 16
#define TAU       0.004f  // rescue margin (> 2x analytic bf16x3 error bound ~1.5e-3)
#define RESCUE_BLOCKS 512
#define RQ        32      // queries per rescue block

// ws layout (bytes):
//   0      : enorm[1024] f32
//   4096   : hist[1024]  u32
//   8192   : counter u32 ; 8196: sse_corr f32 ; 8200: done u32
//   12288  : e_hi[65536] bf16-as-short (128 KB)
//   143360 : e_lo[65536] (128 KB)
//   274432 : idx[65536]  u16 (128 KB)
//   405504 : list[65536] u16 (128 KB)
//   536576 : partials[512] f32

typedef __attribute__((ext_vector_type(8))) short short8;
typedef __attribute__((ext_vector_type(4))) float f32x4;

__device__ __forceinline__ unsigned short f2bf(float x) {
    unsigned u = __float_as_uint(x);
    return (unsigned short)((u + 0x7FFFu + ((u >> 16) & 1u)) >> 16);   // RNE
}
__device__ __forceinline__ float bf2f(unsigned short h) {
    return __uint_as_float(((unsigned)h) << 16);
}
__device__ __forceinline__ void gload_lds16(const void* g, void* l) {
    __builtin_amdgcn_global_load_lds(
        (const __attribute__((address_space(1))) void*)g,
        (__attribute__((address_space(3))) void*)l, 16, 0, 0);
}

// ---------------------------------------------------------------- k_prep ----
__global__ void k_prep(const float* __restrict__ emb, float* __restrict__ enorm,
                       short* __restrict__ ehi, short* __restrict__ elo,
                       unsigned int* __restrict__ hist, unsigned int* __restrict__ counter,
                       float* __restrict__ sse_corr, unsigned int* __restrict__ done) {
    int gid = blockIdx.x * 256 + threadIdx.x;        // 0..16383
    float4 v = *(const float4*)(emb + gid * 4);
    float s = v.x * v.x + v.y * v.y + v.z * v.z + v.w * v.w;
#pragma unroll
    for (int off = 1; off < 16; off <<= 1) s += __shfl_xor(s, off, 64);
    if ((gid & 15) == 0) enorm[gid >> 4] = s;

    float vv[4] = {v.x, v.y, v.z, v.w};
    short h[4], l[4];
#pragma unroll
    for (int j = 0; j < 4; ++j) {
        unsigned short hh = f2bf(vv[j]);
        h[j] = (short)hh;
        l[j] = (short)f2bf(vv[j] - bf2f(hh));
    }
    *(short4*)&ehi[gid * 4] = make_short4(h[0], h[1], h[2], h[3]);
    *(short4*)&elo[gid * 4] = make_short4(l[0], l[1], l[2], l[3]);

    if (gid < K_CODES) hist[gid] = 0u;
    if (gid == 0) { *counter = 0u; *sse_corr = 0.f; *done = 0u; }
}

// -------------------------------------------------------------- k_argmin ----
// 256 thr = 4 waves; QT=128 queries/block x all 1024 codes, bf16x3 MFMA,
// CHUNK=64 double-buffered async staging. Epilogue fused: quantized output
// write (hi+lo reconstruction, err <= 6e-5), hist atomics, SSE partial.
__global__ __launch_bounds__(256, 2)
void k_argmin(const float* __restrict__ x,
              const short* __restrict__ ehi, const short* __restrict__ elo,
              const float* __restrict__ enorm, unsigned short* __restrict__ out_idx,
              unsigned short* __restrict__ list, unsigned int* __restrict__ counter,
              unsigned int* __restrict__ hist, float* __restrict__ partials,
              float* __restrict__ out) {
    __shared__ __align__(16) short es[2][2][CHUNK * CDIM];  // [buf][hi/lo] 32 KB
    __shared__ __align__(16) short xs[2][QT * CDIM];        // 32 KB (reused in epilogue)
    __shared__ float ens[K_CODES];                          // 4 KB
    __shared__ float xnorm[QT];
    __shared__ int   oid[QT];
    __shared__ float spw[2];

    const int tid  = threadIdx.x;
    const int lane = tid & 63;
    const int w    = tid >> 6;
    const int quad = lane >> 4;
    const int col  = lane & 15;

    const int n0  = blockIdx.x * QT;
    const int b   = n0 >> 10;
    const int hw0 = n0 & 1023;        // 128-aligned

    auto stage_async = [&](int chunk, int buf) {
        const int cbS = chunk * (CHUNK * CDIM);
#pragma unroll
        for (int h = 0; h < 2; ++h) {
            const short* tab = h ? elo : ehi;
#pragma unroll
            for (int i = 0; i < 2; ++i) {
                int s   = i * 256 + tid;
                int row = s >> 3, bb = s & 7;
                int g   = bb ^ (row & 7);
                gload_lds16(&tab[cbS + row * 64 + g * 8],
                            (void*)&es[buf][h][s * 8]);
            }
        }
    };

    if (tid < QT) xnorm[tid] = 0.f;
#pragma unroll
    for (int i = 0; i < 4; ++i) ens[i * 256 + tid] = enorm[i * 256 + tid];
    __syncthreads();   // xnorm init visible before atomics

    // stage x tile (transpose + hi/lo split, swizzled) + accumulate ||x||^2
    float nloc[4] = {0.f, 0.f, 0.f, 0.f};
    const int q0s = (tid & 31) * 4;
#pragma unroll
    for (int p = 0; p < 8; ++p) {
        int c = p * 8 + (tid >> 5);
        float4 v = *(const float4*)(x + b * (CDIM * HW_SZ) + c * HW_SZ + hw0 + q0s);
        float vv[4] = {v.x, v.y, v.z, v.w};
#pragma unroll
        for (int j = 0; j < 4; ++j) {
            int q = q0s + j;
            unsigned short h = f2bf(vv[j]);
            unsigned short l = f2bf(vv[j] - bf2f(h));
            int off = q * CDIM + (((c >> 3) ^ (q & 7)) << 3) + (c & 7);
            xs[0][off] = (short)h;
            xs[1][off] = (short)l;
            nloc[j] += vv[j] * vv[j];
        }
    }
#pragma unroll
    for (int j = 0; j < 4; ++j) atomicAdd(&xnorm[q0s + j], nloc[j]);

    stage_async(0, 0);
    __syncthreads();   // xs + xnorm + chunk 0 landed

    // A fragments (register-resident): wave's 2 query tiles of 16
    short8 afr[2][2][2];
#pragma unroll
    for (int rt = 0; rt < 2; ++rt) {
        int m = w * 32 + rt * 16 + col;
#pragma unroll
        for (int kc = 0; kc < 2; ++kc) {
            int bb  = kc * 4 + quad;
            int off = m * CDIM + ((bb ^ (m & 7)) << 3);
            afr[rt][kc][0] = *(const short8*)&xs[0][off];
            afr[rt][kc][1] = *(const short8*)&xs[1][off];
        }
    }

    float d1[8], d2[8];
    int   i1[8];
#pragma unroll
    for (int t = 0; t < 8; ++t) { d1[t] = 3.4e38f; d2[t] = 3.4e38f; i1[t] = 0; }

    for (int chunk = 0; chunk < NCHUNK; ++chunk) {
        const int buf = chunk & 1;
        if (chunk) __syncthreads();
        if (chunk + 1 < NCHUNK) stage_async(chunk + 1, buf ^ 1);

#pragma unroll
        for (int ct = 0; ct < 4; ++ct) {
            const int r = ct * 16 + col;
            short8 bfr[2][2];
#pragma unroll
            for (int kc = 0; kc < 2; ++kc) {
                int bb  = kc * 4 + quad;
                int off = r * CDIM + ((bb ^ (r & 7)) << 3);
                bfr[kc][0] = *(const short8*)&es[buf][0][off];
                bfr[kc][1] = *(const short8*)&es[buf][1][off];
            }
            const int mycode = chunk * CHUNK + r;
            const float en   = ens[mycode];
#pragma unroll
            for (int rt = 0; rt < 2; ++rt) {
                f32x4 acc = {0.f, 0.f, 0.f, 0.f};
                acc = __builtin_amdgcn_mfma_f32_16x16x32_bf16(afr[rt][0][1], bfr[0][0], acc, 0, 0, 0);
                acc = __builtin_amdgcn_mfma_f32_16x16x32_bf16(afr[rt][0][0], bfr[0][1], acc, 0, 0, 0);
                acc = __builtin_amdgcn_mfma_f32_16x16x32_bf16(afr[rt][0][0], bfr[0][0], acc, 0, 0, 0);
                acc = __builtin_amdgcn_mfma_f32_16x16x32_bf16(afr[rt][1][1], bfr[1][0], acc, 0, 0, 0);
                acc = __builtin_amdgcn_mfma_f32_16x16x32_bf16(afr[rt][1][0], bfr[1][1], acc, 0, 0, 0);
                acc = __builtin_amdgcn_mfma_f32_16x16x32_bf16(afr[rt][1][0], bfr[1][0], acc, 0, 0, 0);
#pragma unroll
                for (int reg = 0; reg < 4; ++reg) {
                    int t = rt * 4 + reg;
                    float d   = __builtin_fmaf(acc[reg], -2.f, en);
                    float d1o = d1[t];
                    d2[t] = __builtin_amdgcn_fmed3f(d, d1o, d2[t]);
                    d1[t] = fminf(d, d1o);
                    i1[t] = (d < d1o) ? mycode : i1[t];
                }
            }
        }
    }

    // reduce across 16 cols per query row (codes ascend with col: lex-min ok)
#pragma unroll
    for (int t = 0; t < 8; ++t) {
        float a1 = d1[t], a2 = d2[t];
        int ai = i1[t];
#pragma unroll
        for (int off = 1; off < 16; off <<= 1) {
            float o1 = __shfl_xor(a1, off, 64);
            float o2 = __shfl_xor(a2, off, 64);
            int   oi = __shfl_xor(ai, off, 64);
            if (o1 < a1 || (o1 == a1 && oi < ai)) {
                float loser = a1; a2 = fminf(fminf(a2, o2), loser); a1 = o1; ai = oi;
            } else {
                a2 = fminf(fminf(a2, o2), o1);
            }
        }
        d1[t] = a1; d2[t] = a2; i1[t] = ai;
    }

    // per-query results -> LDS (reuse xs head)
    float* rd1 = (float*)xs;            // [128]
    float* rd2 = rd1 + QT;
    int*   ri  = (int*)(rd2 + QT);
    __syncthreads();
    if (col == 0) {
#pragma unroll
        for (int rt = 0; rt < 2; ++rt)
#pragma unroll
            for (int reg = 0; reg < 4; ++reg) {
                int t = rt * 4 + reg;
                int m = w * 32 + rt * 16 + quad * 4 + reg;
                rd1[m] = d1[t];
                rd2[m] = d2[t];
                ri [m] = i1[t];
            }
    }
    __syncthreads();

    if (tid < QT) {   // waves 0,1: finalize 128 queries
        float a1 = rd1[tid], a2 = rd2[tid];
        int ai = ri[tid];
        oid[tid] = ai;
        out_idx[n0 + tid] = (unsigned short)ai;
        atomicAdd(&hist[ai], 1u);

        bool flag = (a2 - a1) < TAU;
        unsigned long long mask = __ballot(flag);   // per-wave
        int cnt = __popcll(mask);
        unsigned base = 0;
        if (lane == 0 && cnt) base = atomicAdd(counter, (unsigned)cnt);
        base = (unsigned)__shfl((int)base, 0, 64);
        if (flag) {
            int pre = __popcll(mask & ((1ull << lane) - 1ull));
            list[base + pre] = (unsigned short)(n0 + tid);
        }
        float sp = flag ? 0.f : (a1 + xnorm[tid]);
#pragma unroll
        for (int off = 32; off; off >>= 1) sp += __shfl_down(sp, off, 64);
        if (lane == 0) spw[tid >> 6] = sp;
    }
    __syncthreads();
    if (tid == 0) partials[blockIdx.x] = spw[0] + spw[1];

    // ---- fused output write: two 64-query halves through an LDS tile ----
    float* tile = (float*)xs + 512;   // 2 KB offset, 64*72 floats = 18.4 KB
#pragma unroll
    for (int h = 0; h < 2; ++h) {
        {   // gather: thread = (q = tid>>2, j = tid&3) -> 16 channels
            int q = tid >> 2, j = tid & 3;
            int code = oid[h * 64 + q];
            short8 hi0 = *(const short8*)&ehi[code * CDIM + j * 16];
            short8 hi1 = *(const short8*)&ehi[code * CDIM + j * 16 + 8];
            short8 lo0 = *(const short8*)&elo[code * CDIM + j * 16];
            short8 lo1 = *(const short8*)&elo[code * CDIM + j * 16 + 8];
            float* dst = &tile[q * 72 + j * 16];
#pragma unroll
            for (int k = 0; k < 8; ++k) {
                dst[k]     = bf2f((unsigned short)hi0[k]) + bf2f((unsigned short)lo0[k]);
                dst[8 + k] = bf2f((unsigned short)hi1[k]) + bf2f((unsigned short)lo1[k]);
            }
        }
        __syncthreads();
        {   // transposed coalesced write
            int c = tid >> 2;
            float* ob = out + b * (CDIM * HW_SZ) + c * HW_SZ + hw0 + h * 64;
#pragma unroll
            for (int p = 0; p < 4; ++p) {
                int q = ((tid & 3) + p * 4) * 4;   // 0..60
                float4 v;
                v.x = tile[(q + 0) * 72 + c];
                v.y = tile[(q + 1) * 72 + c];
                v.z = tile[(q + 2) * 72 + c];
                v.w = tile[(q + 3) * 72 + c];
                *(float4*)&ob[q] = v;
            }
        }
        if (h == 0) __syncthreads();
    }
}

// -------------------------------------------------------------- k_rescue ----
// Batched exact-fp32 rescue + output-row fixups + ticketed final scalars.
__global__ __launch_bounds__(256, 2)
void k_rescue(const float* __restrict__ x, const float* __restrict__ emb,
              const float* __restrict__ enorm,
              const unsigned short* __restrict__ list,
              const unsigned int* __restrict__ counter,
              unsigned short* __restrict__ out_idx,
              unsigned int* __restrict__ hist, float* __restrict__ sse_corr,
              const float* __restrict__ partials, unsigned int* __restrict__ done,
              float* __restrict__ out) {
    __shared__ __align__(16) float xq[RQ][72];
    __shared__ unsigned short ids[RQ];
    __shared__ float xn[RQ];
    __shared__ float wd[4][RQ];
    __shared__ int   wi[4][RQ];
    __shared__ int   chg_q[RQ], chg_k[RQ];
    __shared__ int   nchg;
    __shared__ unsigned int rank_sh;

    const int tid  = threadIdx.x;
    const int lane = tid & 63;
    const int w    = tid >> 6;
    const unsigned cnt = *counter;
    const unsigned groups = (cnt + RQ - 1) / RQ;

    float en[4];
#pragma unroll
    for (int cd = 0; cd < 4; ++cd) en[cd] = enorm[tid + cd * 256];

    for (unsigned g = blockIdx.x; g < groups; g += RESCUE_BLOCKS) {
        {
            int j = tid >> 3, cpart = tid & 7;
            unsigned qi = g * RQ + j;
            if (qi < cnt) {
                int q = list[qi], b = q >> 10, hw = q & 1023;
                const float* xb = x + b * (CDIM * HW_SZ) + hw;
#pragma unroll
                for (int cc = 0; cc < 8; ++cc)
                    xq[j][cpart * 8 + cc] = xb[(cpart * 8 + cc) * HW_SZ];
            } else {
#pragma unroll
                for (int cc = 0; cc < 8; ++cc) xq[j][cpart * 8 + cc] = 0.f;
            }
            if (tid < RQ) ids[tid] = (g * RQ + tid < cnt) ? list[g * RQ + tid] : (unsigned short)0;
            if (tid == 0) nchg = 0;
        }
        __syncthreads();

        if (tid < RQ) {
            float s = 0.f;
#pragma unroll
            for (int c4 = 0; c4 < 16; ++c4) {
                float4 xv = *(const float4*)&xq[tid][c4 * 4];
                s += xv.x * xv.x + xv.y * xv.y + xv.z * xv.z + xv.w * xv.w;
            }
            xn[tid] = s;
        }

#pragma unroll
        for (int qc = 0; qc < 2; ++qc) {
            float acc[4][16];
#pragma unroll
            for (int cd = 0; cd < 4; ++cd)
#pragma unroll
                for (int qq = 0; qq < 16; ++qq) acc[cd][qq] = 0.f;

            for (int k4 = 0; k4 < 16; ++k4) {
                float4 e[4];
#pragma unroll
                for (int cd = 0; cd < 4; ++cd)
                    e[cd] = *(const float4*)&emb[(tid + cd * 256) * CDIM + k4 * 4];
#pragma unroll
                for (int qq = 0; qq < 16; ++qq) {
                    float4 xv = *(const float4*)&xq[qc * 16 + qq][k4 * 4];
#pragma unroll
                    for (int cd = 0; cd < 4; ++cd) {
                        acc[cd][qq] += e[cd].x * xv.x + e[cd].y * xv.y
                                     + e[cd].z * xv.z + e[cd].w * xv.w;
                    }
                }
            }

#pragma unroll
            for (int qq = 0; qq < 16; ++qq) {
                float bd = 3.4e38f; int bi = 0;
#pragma unroll
                for (int cd = 0; cd < 4; ++cd) {
                    float d = en[cd] - 2.f * acc[cd][qq];
                    int code = tid + cd * 256;
                    if (d < bd) { bd = d; bi = code; }
                }
#pragma unroll
                for (int off = 1; off < 64; off <<= 1) {
                    float od = __shfl_xor(bd, off, 64);
                    int   oi = __shfl_xor(bi, off, 64);
                    if (od < bd || (od == bd && oi < bi)) { bd = od; bi = oi; }
                }
                if (lane == 0) { wd[w][qc * 16 + qq] = bd; wi[w][qc * 16 + qq] = bi; }
            }
        }
        __syncthreads();

        float corr = 0.f;
        if (tid < RQ && g * RQ + tid < cnt) {
            float bd = wd[0][tid]; int bi = wi[0][tid];
#pragma unroll
            for (int ww = 1; ww < 4; ++ww) {
                if (wd[ww][tid] < bd || (wd[ww][tid] == bd && wi[ww][tid] < bi)) {
                    bd = wd[ww][tid]; bi = wi[ww][tid];
                }
            }
            int q = ids[tid];
            int old = out_idx[q];
            if (bi != old) {
                out_idx[q] = (unsigned short)bi;
                atomicAdd(&hist[old], 0xFFFFFFFFu);   // -1
                atomicAdd(&hist[bi], 1u);
                int slot = atomicAdd(&nchg, 1);
                chg_q[slot] = q; chg_k[slot] = bi;
            }
            corr = bd + xn[tid];   // exact (q-x)^2 sum for this flagged query
        }
        if (tid < 64) {
#pragma unroll
            for (int off = 32; off; off >>= 1) corr += __shfl_down(corr, off, 64);
            if (tid == 0 && corr != 0.f) atomicAdd(sse_corr, corr);
        }
        __syncthreads();

        // rewrite output rows of changed queries (exact fp32 emb)
        for (int i = 0; i < nchg; ++i) {
            if (tid < CDIM) {
                int q = chg_q[i], k = chg_k[i];
                int b = q >> 10, hw = q & 1023;
                out[b * (CDIM * HW_SZ) + tid * HW_SZ + hw] = emb[k * CDIM + tid];
            }
        }
        __syncthreads();
    }

    // ---- ticketed final: last block computes loss & perplexity ----
    __threadfence();
    if (tid == 0) rank_sh = atomicAdd(done, 1u);
    __syncthreads();
    if (rank_sh == RESCUE_BLOCKS - 1) {
        float ss = 0.f;
#pragma unroll
        for (int i = 0; i < 2; ++i) ss += partials[i * 256 + tid];   // prev dispatch: safe
        float s = 0.f;
#pragma unroll
        for (int i = 0; i < 4; ++i) {
            unsigned int hv = atomicAdd(&hist[i * 256 + tid], 0u);   // coherent read
            float p = (float)hv * (1.0f / 65536.0f);
            s += p * logf(p + 1e-10f);
        }
        __shared__ float fin[8];
#pragma unroll
        for (int off = 32; off; off >>= 1) {
            ss += __shfl_down(ss, off, 64);
            s  += __shfl_down(s, off, 64);
        }
        if ((tid & 63) == 0) { fin[tid >> 6] = ss; fin[4 + (tid >> 6)] = s; }
        __syncthreads();
        if (tid == 0) {
            float sc  = atomicAdd(sse_corr, 0.f);                    // coherent read
            float sse = fin[0] + fin[1] + fin[2] + fin[3] + sc;
            float ent = fin[4] + fin[5] + fin[6] + fin[7];
            out[OUT_ELEMS]     = 1.25f * sse * (1.0f / (float)OUT_ELEMS);  // loss
            out[OUT_ELEMS + 1] = expf(-ent);                                // perplexity
        }
    }
}

// ---------------------------------------------------------------- launch ----
extern "C" void kernel_launch(void* const* d_in, const int* in_sizes, int n_in,
                              void* d_out, int out_size, void* d_ws, size_t ws_size,
                              hipStream_t stream) {
    const float* x   = (const float*)d_in[0];
    const float* emb = (const float*)d_in[1];
    float* out = (float*)d_out;
    char* ws = (char*)d_ws;
    float*          enorm    = (float*)(ws);
    unsigned int*   hist     = (unsigned int*)(ws + 4096);
    unsigned int*   counter  = (unsigned int*)(ws + 8192);
    float*          sse_corr = (float*)(ws + 8196);
    unsigned int*   done     = (unsigned int*)(ws + 8200);
    short*          ehi      = (short*)(ws + 12288);
    short*          elo      = (short*)(ws + 143360);
    unsigned short* idx      = (unsigned short*)(ws + 274432);
    unsigned short* list     = (unsigned short*)(ws + 405504);
    float*          partials = (float*)(ws + 536576);

    k_prep  <<<64, 256, 0, stream>>>(emb, enorm, ehi, elo, hist, counter, sse_corr, done);
    k_argmin<<<N_TOTAL / QT, 256, 0, stream>>>(x, ehi, elo, enorm, idx, list, counter, hist, partials, out);
    k_rescue<<<RESCUE_BLOCKS, 256, 0, stream>>>(x, emb, enorm, list, counter, idx, hist, sse_corr, partials, done, out);
}

// Round 12
// 149.566 us; speedup vs baseline: 1.2543x; 1.2543x over previous
//
#include <hip/hip_runtime.h>

// Problem constants
#define N_TOTAL   65536   // B*H*W = 64*32*32
#define HW_SZ     1024    // H*W
#define CDIM      64      // embedding dim (= C)
#define K_CODES   1024
#define OUT_ELEMS 4194304 // 64*64*32*32
#define QT        128     // queries per argmin block
#define CHUNK     64      // codes per LDS chunk (double-buffered)
#define NCHUNK    (K_CODES / CHUNK)   // 16
#define TAU       0.004f  // rescue margin (> 2x analytic bf16x3 error bound ~1.5e-3)

// ws layout (bytes):
//   0      : enorm[1024] f32
//   4096   : hist[1024]  u32
//   12288  : e_hi[65536] bf16-as-short (128 KB)
//   143360 : e_lo[65536] (128 KB)
//   274432 : partials[512] f32

typedef __attribute__((ext_vector_type(8))) short short8;
typedef __attribute__((ext_vector_type(4))) float f32x4;

__device__ __forceinline__ unsigned short f2bf(float x) {
    unsigned u = __float_as_uint(x);
    return (unsigned short)((u + 0x7FFFu + ((u >> 16) & 1u)) >> 16);   // RNE
}
__device__ __forceinline__ float bf2f(unsigned short h) {
    return __uint_as_float(((unsigned)h) << 16);
}
__device__ __forceinline__ void gload_lds16(const void* g, void* l) {
    __builtin_amdgcn_global_load_lds(
        (const __attribute__((address_space(1))) void*)g,
        (__attribute__((address_space(3))) void*)l, 16, 0, 0);
}

// ---------------------------------------------------------------- k_prep ----
__global__ void k_prep(const float* __restrict__ emb, float* __restrict__ enorm,
                       short* __restrict__ ehi, short* __restrict__ elo,
                       unsigned int* __restrict__ hist) {
    int gid = blockIdx.x * 256 + threadIdx.x;        // 0..16383
    float4 v = *(const float4*)(emb + gid * 4);
    float s = v.x * v.x + v.y * v.y + v.z * v.z + v.w * v.w;
#pragma unroll
    for (int off = 1; off < 16; off <<= 1) s += __shfl_xor(s, off, 64);
    if ((gid & 15) == 0) enorm[gid >> 4] = s;

    float vv[4] = {v.x, v.y, v.z, v.w};
    short h[4], l[4];
#pragma unroll
    for (int j = 0; j < 4; ++j) {
        unsigned short hh = f2bf(vv[j]);
        h[j] = (short)hh;
        l[j] = (short)f2bf(vv[j] - bf2f(hh));
    }
    *(short4*)&ehi[gid * 4] = make_short4(h[0], h[1], h[2], h[3]);
    *(short4*)&elo[gid * 4] = make_short4(l[0], l[1], l[2], l[3]);

    if (gid < K_CODES) hist[gid] = 0u;
}

// -------------------------------------------------------------- k_argmin ----
// 256 thr = 4 waves; QT=128 queries/block x all 1024 codes, bf16x3 MFMA,
// CHUNK=64 double-buffered async staging. Post-merge, flagged queries
// (margin < TAU) are re-solved EXACTLY in fp32 in-block (no rescue dispatch).
// Epilogue on final indices: hist atomics, SSE partial, transposed out-write.
__global__ __launch_bounds__(256, 2)
void k_argmin(const float* __restrict__ x, const float* __restrict__ emb,
              const short* __restrict__ ehi, const short* __restrict__ elo,
              const float* __restrict__ enorm,
              unsigned int* __restrict__ hist, float* __restrict__ partials,
              float* __restrict__ out) {
    __shared__ __align__(16) short es[2][2][CHUNK * CDIM];  // [buf][hi/lo] 32 KB
    __shared__ __align__(16) short xs[2][QT * CDIM];        // 32 KB (reused after K-loop)
    __shared__ float ens[K_CODES];                          // 4 KB (exact fp32 ||e||^2)
    __shared__ float xnorm[QT];
    __shared__ int   oid[QT];
    __shared__ int   nflag;
    __shared__ float wdd[4];
    __shared__ int   wii[4];
    __shared__ float spw[2];

    const int tid  = threadIdx.x;
    const int lane = tid & 63;
    const int w    = tid >> 6;
    const int quad = lane >> 4;
    const int col  = lane & 15;

    const int n0  = blockIdx.x * QT;
    const int b   = n0 >> 10;
    const int hw0 = n0 & 1023;        // 128-aligned

    auto stage_async = [&](int chunk, int buf) {
        const int cbS = chunk * (CHUNK * CDIM);
#pragma unroll
        for (int h = 0; h < 2; ++h) {
            const short* tab = h ? elo : ehi;
#pragma unroll
            for (int i = 0; i < 2; ++i) {
                int s   = i * 256 + tid;
                int row = s >> 3, bb = s & 7;
                int g   = bb ^ (row & 7);
                gload_lds16(&tab[cbS + row * 64 + g * 8],
                            (void*)&es[buf][h][s * 8]);
            }
        }
    };

    if (tid < QT) xnorm[tid] = 0.f;
#pragma unroll
    for (int i = 0; i < 4; ++i) ens[i * 256 + tid] = enorm[i * 256 + tid];
    __syncthreads();   // xnorm init visible before atomics

    // stage x tile (transpose + hi/lo split, swizzled) + accumulate ||x||^2
    float nloc[4] = {0.f, 0.f, 0.f, 0.f};
    const int q0s = (tid & 31) * 4;
#pragma unroll
    for (int p = 0; p < 8; ++p) {
        int c = p * 8 + (tid >> 5);
        float4 v = *(const float4*)(x + b * (CDIM * HW_SZ) + c * HW_SZ + hw0 + q0s);
        float vv[4] = {v.x, v.y, v.z, v.w};
#pragma unroll
        for (int j = 0; j < 4; ++j) {
            int q = q0s + j;
            unsigned short h = f2bf(vv[j]);
            unsigned short l = f2bf(vv[j] - bf2f(h));
            int off = q * CDIM + (((c >> 3) ^ (q & 7)) << 3) + (c & 7);
            xs[0][off] = (short)h;
            xs[1][off] = (short)l;
            nloc[j] += vv[j] * vv[j];
        }
    }
#pragma unroll
    for (int j = 0; j < 4; ++j) atomicAdd(&xnorm[q0s + j], nloc[j]);

    stage_async(0, 0);
    __syncthreads();   // xs + xnorm + chunk 0 landed

    // A fragments (register-resident): wave's 2 query tiles of 16
    short8 afr[2][2][2];
#pragma unroll
    for (int rt = 0; rt < 2; ++rt) {
        int m = w * 32 + rt * 16 + col;
#pragma unroll
        for (int kc = 0; kc < 2; ++kc) {
            int bb  = kc * 4 + quad;
            int off = m * CDIM + ((bb ^ (m & 7)) << 3);
            afr[rt][kc][0] = *(const short8*)&xs[0][off];
            afr[rt][kc][1] = *(const short8*)&xs[1][off];
        }
    }

    float d1[8], d2[8];
    int   i1[8];
#pragma unroll
    for (int t = 0; t < 8; ++t) { d1[t] = 3.4e38f; d2[t] = 3.4e38f; i1[t] = 0; }

    for (int chunk = 0; chunk < NCHUNK; ++chunk) {
        const int buf = chunk & 1;
        if (chunk) __syncthreads();
        if (chunk + 1 < NCHUNK) stage_async(chunk + 1, buf ^ 1);

#pragma unroll
        for (int ct = 0; ct < 4; ++ct) {
            const int r = ct * 16 + col;
            short8 bfr[2][2];
#pragma unroll
            for (int kc = 0; kc < 2; ++kc) {
                int bb  = kc * 4 + quad;
                int off = r * CDIM + ((bb ^ (r & 7)) << 3);
                bfr[kc][0] = *(const short8*)&es[buf][0][off];
                bfr[kc][1] = *(const short8*)&es[buf][1][off];
            }
            const int mycode = chunk * CHUNK + r;
            const float en   = ens[mycode];
#pragma unroll
            for (int rt = 0; rt < 2; ++rt) {
                f32x4 acc = {0.f, 0.f, 0.f, 0.f};
                acc = __builtin_amdgcn_mfma_f32_16x16x32_bf16(afr[rt][0][1], bfr[0][0], acc, 0, 0, 0);
                acc = __builtin_amdgcn_mfma_f32_16x16x32_bf16(afr[rt][0][0], bfr[0][1], acc, 0, 0, 0);
                acc = __builtin_amdgcn_mfma_f32_16x16x32_bf16(afr[rt][0][0], bfr[0][0], acc, 0, 0, 0);
                acc = __builtin_amdgcn_mfma_f32_16x16x32_bf16(afr[rt][1][1], bfr[1][0], acc, 0, 0, 0);
                acc = __builtin_amdgcn_mfma_f32_16x16x32_bf16(afr[rt][1][0], bfr[1][1], acc, 0, 0, 0);
                acc = __builtin_amdgcn_mfma_f32_16x16x32_bf16(afr[rt][1][0], bfr[1][0], acc, 0, 0, 0);
#pragma unroll
                for (int reg = 0; reg < 4; ++reg) {
                    int t = rt * 4 + reg;
                    float d   = __builtin_fmaf(acc[reg], -2.f, en);
                    float d1o = d1[t];
                    d2[t] = __builtin_amdgcn_fmed3f(d, d1o, d2[t]);
                    d1[t] = fminf(d, d1o);
                    i1[t] = (d < d1o) ? mycode : i1[t];
                }
            }
        }
    }

    // reduce across 16 cols per query row (codes ascend with col: lex-min ok)
#pragma unroll
    for (int t = 0; t < 8; ++t) {
        float a1 = d1[t], a2 = d2[t];
        int ai = i1[t];
#pragma unroll
        for (int off = 1; off < 16; off <<= 1) {
            float o1 = __shfl_xor(a1, off, 64);
            float o2 = __shfl_xor(a2, off, 64);
            int   oi = __shfl_xor(ai, off, 64);
            if (o1 < a1 || (o1 == a1 && oi < ai)) {
                float loser = a1; a2 = fminf(fminf(a2, o2), loser); a1 = o1; ai = oi;
            } else {
                a2 = fminf(fminf(a2, o2), o1);
            }
        }
        d1[t] = a1; d2[t] = a2; i1[t] = ai;
    }

    // per-query results -> LDS (alias into xs; disjoint regions)
    float* rd1   = (float*)xs;                       // bytes 0..511
    float* rd2   = rd1 + QT;                         // 512..1023
    int*   ri    = (int*)(rd2 + QT);                 // 1024..1535
    int*   flist = (int*)((char*)xs + 1536);         // 1536..2047
    float* xqf   = (float*)((char*)xs + 2048);       // 2048..2303
    float* tile  = (float*)((char*)xs + 2560);       // 2560..20991 (64*72 f32)

    __syncthreads();
    if (tid == 0) nflag = 0;
    if (col == 0) {
#pragma unroll
        for (int rt = 0; rt < 2; ++rt)
#pragma unroll
            for (int reg = 0; reg < 4; ++reg) {
                int t = rt * 4 + reg;
                int m = w * 32 + rt * 16 + quad * 4 + reg;
                rd1[m] = d1[t];
                rd2[m] = d2[t];
                ri [m] = i1[t];
            }
    }
    __syncthreads();

    // flag queries with margin < TAU for exact in-block re-solve
    if (tid < QT) {
        if (rd2[tid] - rd1[tid] < TAU) {
            int slot = atomicAdd(&nflag, 1);
            flist[slot] = tid;
        }
    }
    __syncthreads();

    // ---- in-block exact fp32 rescue (avg nflag ~0-1 per block) ----
    for (int f = 0; f < nflag; ++f) {
        const int q = flist[f];
        if (tid < CDIM) xqf[tid] = x[b * (CDIM * HW_SZ) + tid * HW_SZ + hw0 + q];
        __syncthreads();
        float dm = 3.4e38f; int im = 0;
#pragma unroll
        for (int cd = 0; cd < 4; ++cd) {
            const int k = tid + cd * 256;            // codes ascend with cd
            const float4* er = (const float4*)(emb + k * CDIM);
            const float4* xr = (const float4*)xqf;
            float dot = 0.f;
#pragma unroll
            for (int c4 = 0; c4 < 16; ++c4) {
                float4 e = er[c4], xv = xr[c4];
                dot += e.x * xv.x + e.y * xv.y + e.z * xv.z + e.w * xv.w;
            }
            float d = ens[k] - 2.f * dot;            // exact fp32
            if (d < dm) { dm = d; im = k; }
        }
#pragma unroll
        for (int off = 1; off < 64; off <<= 1) {
            float od = __shfl_xor(dm, off, 64);
            int   oi = __shfl_xor(im, off, 64);
            if (od < dm || (od == dm && oi < im)) { dm = od; im = oi; }
        }
        if (lane == 0) { wdd[w] = dm; wii[w] = im; }
        __syncthreads();
        if (tid == 0) {
            float bd = wdd[0]; int bi = wii[0];
#pragma unroll
            for (int ww = 1; ww < 4; ++ww)
                if (wdd[ww] < bd || (wdd[ww] == bd && wii[ww] < bi)) { bd = wdd[ww]; bi = wii[ww]; }
            rd1[q] = bd; ri[q] = bi;                 // final exact result
        }
        __syncthreads();
    }

    // ---- epilogue on FINAL indices: hist, SSE partial ----
    if (tid < QT) {
        int ai = ri[tid];
        oid[tid] = ai;
        atomicAdd(&hist[ai], 1u);
        float sp = rd1[tid] + xnorm[tid];            // ||q-x||^2 (exact for rescued)
#pragma unroll
        for (int off = 32; off; off >>= 1) sp += __shfl_down(sp, off, 64);
        if (lane == 0) spw[tid >> 6] = sp;
    }
    __syncthreads();
    if (tid == 0) partials[blockIdx.x] = spw[0] + spw[1];

    // ---- fused output write: two 64-query halves through an LDS tile ----
#pragma unroll
    for (int h = 0; h < 2; ++h) {
        {   // gather: thread = (q = tid>>2, j = tid&3) -> 16 channels
            int q = tid >> 2, j = tid & 3;
            int code = oid[h * 64 + q];
            short8 hi0 = *(const short8*)&ehi[code * CDIM + j * 16];
            short8 hi1 = *(const short8*)&ehi[code * CDIM + j * 16 + 8];
            short8 lo0 = *(const short8*)&elo[code * CDIM + j * 16];
            short8 lo1 = *(const short8*)&elo[code * CDIM + j * 16 + 8];
            float* dst = &tile[q * 72 + j * 16];
#pragma unroll
            for (int k = 0; k < 8; ++k) {
                dst[k]     = bf2f((unsigned short)hi0[k]) + bf2f((unsigned short)lo0[k]);
                dst[8 + k] = bf2f((unsigned short)hi1[k]) + bf2f((unsigned short)lo1[k]);
            }
        }
        __syncthreads();
        {   // transposed coalesced write
            int c = tid >> 2;
            float* ob = out + b * (CDIM * HW_SZ) + c * HW_SZ + hw0 + h * 64;
#pragma unroll
            for (int p = 0; p < 4; ++p) {
                int q = ((tid & 3) + p * 4) * 4;   // 0..60
                float4 v;
                v.x = tile[(q + 0) * 72 + c];
                v.y = tile[(q + 1) * 72 + c];
                v.z = tile[(q + 2) * 72 + c];
                v.w = tile[(q + 3) * 72 + c];
                *(float4*)&ob[q] = v;
            }
        }
        if (h == 0) __syncthreads();
    }
}

// --------------------------------------------------------------- k_final ----
// 1 block; reads partials (512) + hist (1024) from previous dispatches.
__global__ void k_final(const float* __restrict__ partials,
                        const unsigned int* __restrict__ hist,
                        float* __restrict__ out) {
    int tid = threadIdx.x;   // 256
    float ss = 0.f;
#pragma unroll
    for (int i = 0; i < 2; ++i) ss += partials[i * 256 + tid];
    float s = 0.f;
#pragma unroll
    for (int i = 0; i < 4; ++i) {
        float p = (float)hist[i * 256 + tid] * (1.0f / 65536.0f);
        s += p * logf(p + 1e-10f);
    }
    __shared__ float fin[8];
#pragma unroll
    for (int off = 32; off; off >>= 1) {
        ss += __shfl_down(ss, off, 64);
        s  += __shfl_down(s, off, 64);
    }
    if ((tid & 63) == 0) { fin[tid >> 6] = ss; fin[4 + (tid >> 6)] = s; }
    __syncthreads();
    if (tid == 0) {
        float sse = fin[0] + fin[1] + fin[2] + fin[3];
        float ent = fin[4] + fin[5] + fin[6] + fin[7];
        out[OUT_ELEMS]     = 1.25f * sse * (1.0f / (float)OUT_ELEMS);  // loss
        out[OUT_ELEMS + 1] = expf(-ent);                                // perplexity
    }
}

// ---------------------------------------------------------------- launch ----
extern "C" void kernel_launch(void* const* d_in, const int* in_sizes, int n_in,
                              void* d_out, int out_size, void* d_ws, size_t ws_size,
                              hipStream_t stream) {
    const float* x   = (const float*)d_in[0];
    const float* emb = (const float*)d_in[1];
    float* out = (float*)d_out;
    char* ws = (char*)d_ws;
    float*        enorm    = (float*)(ws);
    unsigned int* hist     = (unsigned int*)(ws + 4096);
    short*        ehi      = (short*)(ws + 12288);
    short*        elo      = (short*)(ws + 143360);
    float*        partials = (float*)(ws + 274432);

    k_prep  <<<64, 256, 0, stream>>>(emb, enorm, ehi, elo, hist);
    k_argmin<<<N_TOTAL / QT, 256, 0, stream>>>(x, emb, ehi, elo, enorm, hist, partials, out);
    k_final <<<1, 256, 0, stream>>>(partials, hist, out);
}